// Round 1
// baseline (640.676 us; speedup 1.0000x reference)
//
#include <hip/hip_runtime.h>
#include <stdint.h>

// ---------- types ----------
typedef unsigned short ushort_t;
typedef __bf16 bf16x8 __attribute__((ext_vector_type(8)));
typedef float f32x4 __attribute__((ext_vector_type(4)));
typedef float float4v __attribute__((ext_vector_type(4)));
typedef unsigned short ushort4v __attribute__((ext_vector_type(4)));

#define T_SEQ 2048
#define D_MODEL 2048
#define N_HEADS 16
#define HEAD_D 128
#define BATCH 2
#define M_ROWS (BATCH * T_SEQ)   // 4096

__device__ __forceinline__ ushort_t f2bf(float f) {
    unsigned u = __builtin_bit_cast(unsigned, f);
    u += 0x7fffu + ((u >> 16) & 1u);   // RNE; inputs are finite/sane
    return (ushort_t)(u >> 16);
}
__device__ __forceinline__ float bf2f(ushort_t h) {
    unsigned u = ((unsigned)h) << 16;
    return __builtin_bit_cast(float, u);
}

__device__ __forceinline__ void gload16(const ushort_t* g, ushort_t* l) {
    __builtin_amdgcn_global_load_lds(
        (const __attribute__((address_space(1))) void*)g,
        (__attribute__((address_space(3))) void*)l,
        16, 0, 0);
}

// ---------- cast x: f32 -> bf16 ----------
__global__ void cast_x_kernel(const float* __restrict__ x, ushort_t* __restrict__ xb, int n4) {
    int i = blockIdx.x * blockDim.x + threadIdx.x;
    if (i >= n4) return;
    float4v v = *(const float4v*)(x + (size_t)i * 4);
    ushort4v o;
    o[0] = f2bf(v[0]); o[1] = f2bf(v[1]); o[2] = f2bf(v[2]); o[3] = f2bf(v[3]);
    *(ushort4v*)(xb + (size_t)i * 4) = o;
}

// ---------- transpose + cast: W f32 [K][N] -> Wt bf16 [N][K] ----------
__global__ void tcast_kernel(const float* __restrict__ W, ushort_t* __restrict__ Wt, int K, int N) {
    __shared__ float tile[32][33];
    int n0 = blockIdx.x * 32, k0 = blockIdx.y * 32;
    int tx = threadIdx.x, ty = threadIdx.y;  // block (32,8)
#pragma unroll
    for (int i = 0; i < 4; ++i)
        tile[ty + i * 8][tx] = W[(size_t)(k0 + ty + i * 8) * N + n0 + tx];
    __syncthreads();
#pragma unroll
    for (int i = 0; i < 4; ++i)
        Wt[(size_t)(n0 + ty + i * 8) * K + k0 + tx] = f2bf(tile[tx][ty + i * 8]);
}

// ---------- GEMM: C[M,N] = A[M,K] (bf16 rm) x Bt[N,K] (bf16 rm, = B^T) ----------
// 128x128 tile, BK=64, 256 thr = 4 waves (2x2 of 64x64), mfma 16x16x32 bf16.
// EPI 0: scatter to q/k/vt (bf16).  EPI 1: sigmoid gate * atty -> y (bf16).  EPI 2: f32 out.
template <int EPI>
__global__ __launch_bounds__(256) void gemm_bt(
    const ushort_t* __restrict__ A, const ushort_t* __restrict__ Bt,
    int M, int N, int K,
    ushort_t* __restrict__ o_q, ushort_t* __restrict__ o_k, ushort_t* __restrict__ o_vt,
    const float* __restrict__ b_gate, const ushort_t* __restrict__ atty,
    ushort_t* __restrict__ o_y, float* __restrict__ o_f32)
{
    __shared__ ushort_t As[128 * 64];
    __shared__ ushort_t Bs[128 * 64];
    const int tid = threadIdx.x;
    const int wid = tid >> 6, l = tid & 63;
    const int ln = l & 15, hi = l >> 4;
    const int wm = wid >> 1, wn = wid & 1;
    const int m0 = blockIdx.y * 128, n0 = blockIdx.x * 128;

    f32x4 acc[4][4];
#pragma unroll
    for (int m = 0; m < 4; ++m)
#pragma unroll
        for (int n = 0; n < 4; ++n) acc[m][n] = (f32x4){0.f, 0.f, 0.f, 0.f};

    const ushort_t* Ab = A + (size_t)(m0 + (tid >> 3)) * K + (tid & 7) * 8;
    const ushort_t* Bb = Bt + (size_t)(n0 + (tid >> 3)) * K + (tid & 7) * 8;
    ushort_t* As_w = As + wid * 512;   // wave-uniform LDS base (lane i lands at +i*16B)
    ushort_t* Bs_w = Bs + wid * 512;

    for (int kt = 0; kt < K; kt += 64) {
        __syncthreads();
#pragma unroll
        for (int i = 0; i < 4; ++i) {
            gload16(Ab + (size_t)(i * 32) * K + kt, As_w + i * 2048);
            gload16(Bb + (size_t)(i * 32) * K + kt, Bs_w + i * 2048);
        }
        asm volatile("s_waitcnt vmcnt(0)" ::: "memory");
        __syncthreads();
#pragma unroll
        for (int kk = 0; kk < 2; ++kk) {
            bf16x8 af[4], bfg[4];
#pragma unroll
            for (int m = 0; m < 4; ++m)
                af[m] = *(const bf16x8*)(As + (wm * 64 + m * 16 + ln) * 64 + kk * 32 + hi * 8);
#pragma unroll
            for (int n = 0; n < 4; ++n)
                bfg[n] = *(const bf16x8*)(Bs + (wn * 64 + n * 16 + ln) * 64 + kk * 32 + hi * 8);
#pragma unroll
            for (int m = 0; m < 4; ++m)
#pragma unroll
                for (int n = 0; n < 4; ++n)
                    acc[m][n] = __builtin_amdgcn_mfma_f32_16x16x32_bf16(af[m], bfg[n], acc[m][n], 0, 0, 0);
        }
    }

    // epilogue — C layout: row = (lane>>4)*4 + j, col = lane&15 (m89-verified)
    if (EPI == 0) {
        const int sec = n0 >> 11;                // 0=q,1=k,2=v
        const int h = (n0 & 2047) >> 7;          // head (uniform per block)
#pragma unroll
        for (int m = 0; m < 4; ++m)
#pragma unroll
            for (int n = 0; n < 4; ++n)
#pragma unroll
                for (int j = 0; j < 4; ++j) {
                    int grow = m0 + wm * 64 + m * 16 + hi * 4 + j;   // b*T + t
                    int b = grow >> 11, t = grow & 2047;
                    int dd = wn * 64 + n * 16 + ln;
                    ushort_t val = f2bf(acc[m][n][j]);
                    size_t bh = (size_t)(b * N_HEADS + h);
                    if (sec == 0)      o_q[(bh * T_SEQ + t) * HEAD_D + dd] = val;
                    else if (sec == 1) o_k[(bh * T_SEQ + t) * HEAD_D + dd] = val;
                    else               o_vt[(bh * HEAD_D + dd) * T_SEQ + t] = val;
                }
    } else if (EPI == 1) {
#pragma unroll
        for (int m = 0; m < 4; ++m)
#pragma unroll
            for (int n = 0; n < 4; ++n)
#pragma unroll
                for (int j = 0; j < 4; ++j) {
                    int grow = m0 + wm * 64 + m * 16 + hi * 4 + j;
                    int gcol = n0 + wn * 64 + n * 16 + ln;
                    float g = acc[m][n][j] + b_gate[gcol];
                    g = 1.0f / (1.0f + __expf(-g));
                    size_t idx = (size_t)grow * D_MODEL + gcol;
                    o_y[idx] = f2bf(bf2f(atty[idx]) * g);
                }
    } else {
#pragma unroll
        for (int m = 0; m < 4; ++m)
#pragma unroll
            for (int n = 0; n < 4; ++n)
#pragma unroll
                for (int j = 0; j < 4; ++j) {
                    int grow = m0 + wm * 64 + m * 16 + hi * 4 + j;
                    int gcol = n0 + wn * 64 + n * 16 + ln;
                    o_f32[(size_t)grow * N + gcol] = acc[m][n][j];
                }
    }
}

// ---------- RMSNorm + RoPE, in place on q and k [B,H,T,128] ----------
// one wave per (b,h,t) row; lane j holds the RoPE pair (j, j+64)
__global__ __launch_bounds__(256) void rmsrope_kernel(ushort_t* __restrict__ qb, ushort_t* __restrict__ kb) {
    int wid = threadIdx.x >> 6, l = threadIdx.x & 63;
    int row = blockIdx.x * 4 + wid;          // (b*H + h)*T + t
    int t = row & (T_SEQ - 1);
    size_t base = (size_t)row * HEAD_D;

    // angle: inv_freq = 10000^(-l/64) = exp(-l * ln(1e4)/64)
    float ang = (float)t * expf(-(float)l * 0.14391156f);
    float sv, cv;
    sincosf(ang, &sv, &cv);

    // q
    float a = bf2f(qb[base + l]), b = bf2f(qb[base + 64 + l]);
    float ss = a * a + b * b;
#pragma unroll
    for (int d = 1; d < 64; d <<= 1) ss += __shfl_xor(ss, d);
    float r = rsqrtf(ss * (1.0f / 128.0f) + 1e-6f);
    a *= r; b *= r;
    qb[base + l]      = f2bf(a * cv - b * sv);
    qb[base + 64 + l] = f2bf(a * sv + b * cv);

    // k
    a = bf2f(kb[base + l]); b = bf2f(kb[base + 64 + l]);
    ss = a * a + b * b;
#pragma unroll
    for (int d = 1; d < 64; d <<= 1) ss += __shfl_xor(ss, d);
    r = rsqrtf(ss * (1.0f / 128.0f) + 1e-6f);
    a *= r; b *= r;
    kb[base + l]      = f2bf(a * cv - b * sv);
    kb[base + 64 + l] = f2bf(a * sv + b * cv);
}

// ---------- causal flash attention ----------
// grid (16 qtiles, 32 bh), 256 thr = 4 waves; each wave owns 32 q-rows.
// K,V read from global (L2-resident per head). P transposed via padded LDS.
// writes att output directly in [B,T,D] layout (gate transpose cancels).
__global__ __launch_bounds__(256) void flash_kernel(
    const ushort_t* __restrict__ qb, const ushort_t* __restrict__ kb,
    const ushort_t* __restrict__ vt, ushort_t* __restrict__ atty)
{
    const int qt = blockIdx.x, bh = blockIdx.y;
    const int wid = threadIdx.x >> 6, l = threadIdx.x & 63;
    const int ln = l & 15, hi = l >> 4;
    const int q0 = qt * 128 + wid * 32;

    const ushort_t* Q  = qb + (size_t)bh * T_SEQ * HEAD_D;
    const ushort_t* Kp = kb + (size_t)bh * T_SEQ * HEAD_D;
    const ushort_t* Vp = vt + (size_t)bh * HEAD_D * T_SEQ;

    __shared__ ushort_t p_all[4][32][72];   // +8 pad: breaks 128B-stride bank conflict
    ushort_t (*p_lds)[72] = p_all[wid];

    bf16x8 qf[2][4];
#pragma unroll
    for (int m = 0; m < 2; ++m)
#pragma unroll
        for (int kk = 0; kk < 4; ++kk)
            qf[m][kk] = *(const bf16x8*)(Q + (size_t)(q0 + m * 16 + ln) * HEAD_D + kk * 32 + hi * 8);

    f32x4 acc_o[2][8];
#pragma unroll
    for (int m = 0; m < 2; ++m)
#pragma unroll
        for (int nd = 0; nd < 8; ++nd) acc_o[m][nd] = (f32x4){0.f, 0.f, 0.f, 0.f};
    float rm[2][4], rl[2][4];
#pragma unroll
    for (int m = 0; m < 2; ++m)
#pragma unroll
        for (int j = 0; j < 4; ++j) { rm[m][j] = -1e30f; rl[m][j] = 0.f; }

    const float scale = 0.08838834764831845f;   // 1/sqrt(128)
    const int kv_last = q0 + 31;

    for (int kv0 = 0; kv0 <= kv_last; kv0 += 64) {
        // ---- S = Q K^T (C layout) ----
        f32x4 sa[2][4];
#pragma unroll
        for (int m = 0; m < 2; ++m)
#pragma unroll
            for (int n = 0; n < 4; ++n) sa[m][n] = (f32x4){0.f, 0.f, 0.f, 0.f};
#pragma unroll
        for (int kk = 0; kk < 4; ++kk) {
            bf16x8 kf[4];
#pragma unroll
            for (int n = 0; n < 4; ++n)
                kf[n] = *(const bf16x8*)(Kp + (size_t)(kv0 + n * 16 + ln) * HEAD_D + kk * 32 + hi * 8);
#pragma unroll
            for (int m = 0; m < 2; ++m)
#pragma unroll
                for (int n = 0; n < 4; ++n)
                    sa[m][n] = __builtin_amdgcn_mfma_f32_16x16x32_bf16(qf[m][kk], kf[n], sa[m][n], 0, 0, 0);
        }
        // ---- mask + online softmax (rows: m*16 + hi*4 + j; cols: n*16 + ln) ----
#pragma unroll
        for (int m = 0; m < 2; ++m) {
#pragma unroll
            for (int j = 0; j < 4; ++j) {
                const int qrow = q0 + m * 16 + hi * 4 + j;
                float pv[4];
                float mx = -1e30f;
#pragma unroll
                for (int n = 0; n < 4; ++n) {
                    int kv = kv0 + n * 16 + ln;
                    float v = sa[m][n][j] * scale;
                    v = (kv <= qrow) ? v : -1e30f;
                    pv[n] = v;
                    mx = fmaxf(mx, v);
                }
#pragma unroll
                for (int d = 1; d < 16; d <<= 1) mx = fmaxf(mx, __shfl_xor(mx, d));
                float mnew = fmaxf(rm[m][j], mx);
                float corr = __expf(rm[m][j] - mnew);
                float psum = 0.f;
#pragma unroll
                for (int n = 0; n < 4; ++n) {
                    float p = __expf(pv[n] - mnew);
                    psum += p;
                    p_lds[m * 16 + hi * 4 + j][n * 16 + ln] = f2bf(p);
                }
#pragma unroll
                for (int d = 1; d < 16; d <<= 1) psum += __shfl_xor(psum, d);
                rl[m][j] = rl[m][j] * corr + psum;
                rm[m][j] = mnew;
#pragma unroll
                for (int nd = 0; nd < 8; ++nd) acc_o[m][nd][j] *= corr;
            }
        }
        asm volatile("s_waitcnt lgkmcnt(0)" ::: "memory");  // P writes visible before A-frag reads (same wave)
        // ---- O += P V ----
#pragma unroll
        for (int kk2 = 0; kk2 < 2; ++kk2) {
            bf16x8 pf0 = *(const bf16x8*)(&p_lds[ln][kk2 * 32 + hi * 8]);
            bf16x8 pf1 = *(const bf16x8*)(&p_lds[16 + ln][kk2 * 32 + hi * 8]);
#pragma unroll
            for (int nd = 0; nd < 8; ++nd) {
                bf16x8 vf = *(const bf16x8*)(Vp + (size_t)(nd * 16 + ln) * T_SEQ + kv0 + kk2 * 32 + hi * 8);
                acc_o[0][nd] = __builtin_amdgcn_mfma_f32_16x16x32_bf16(pf0, vf, acc_o[0][nd], 0, 0, 0);
                acc_o[1][nd] = __builtin_amdgcn_mfma_f32_16x16x32_bf16(pf1, vf, acc_o[1][nd], 0, 0, 0);
            }
        }
    }

    // epilogue: atty[b][t][h*128 + dcol] = acc_o / rl
    const int b = bh >> 4, h = bh & 15;
#pragma unroll
    for (int m = 0; m < 2; ++m)
#pragma unroll
        for (int nd = 0; nd < 8; ++nd)
#pragma unroll
            for (int j = 0; j < 4; ++j) {
                int tq = q0 + m * 16 + hi * 4 + j;
                float val = acc_o[m][nd][j] / rl[m][j];
                atty[((size_t)(b * T_SEQ + tq)) * D_MODEL + h * HEAD_D + nd * 16 + ln] = f2bf(val);
            }
}

// ---------- launch ----------
extern "C" void kernel_launch(void* const* d_in, const int* in_sizes, int n_in,
                              void* d_out, int out_size, void* d_ws, size_t ws_size,
                              hipStream_t stream) {
    const float* x      = (const float*)d_in[0];
    const float* W_qkv  = (const float*)d_in[1];
    const float* W_out  = (const float*)d_in[2];
    const float* W_gate = (const float*)d_in[3];
    const float* b_gate = (const float*)d_in[4];
    // d_in[5] = mask: always causal tril; implemented directly.
    float* out = (float*)d_out;

    char* ws = (char*)d_ws;
    size_t off = 0;
    ushort_t* xb     = (ushort_t*)(ws + off); off += (size_t)M_ROWS * D_MODEL * 2;          // 16 MB
    ushort_t* wqkvT  = (ushort_t*)(ws + off); off += (size_t)3 * D_MODEL * D_MODEL * 2;     // 24 MB
    ushort_t* wgateT = (ushort_t*)(ws + off); off += (size_t)D_MODEL * D_MODEL * 2;         // 8 MB
    ushort_t* woutT  = (ushort_t*)(ws + off); off += (size_t)D_MODEL * D_MODEL * 2;         // 8 MB
    ushort_t* q_b    = (ushort_t*)(ws + off); off += (size_t)M_ROWS * D_MODEL * 2;          // 16 MB
    ushort_t* k_b    = (ushort_t*)(ws + off); off += (size_t)M_ROWS * D_MODEL * 2;          // 16 MB
    ushort_t* v_t    = (ushort_t*)(ws + off); off += (size_t)M_ROWS * D_MODEL * 2;          // 16 MB
    ushort_t* atty   = (ushort_t*)(ws + off); off += (size_t)M_ROWS * D_MODEL * 2;          // 16 MB
    ushort_t* y_b    = (ushort_t*)(ws + off); off += (size_t)M_ROWS * D_MODEL * 2;          // 16 MB

    // 1. cast x to bf16
    cast_x_kernel<<<8192, 256, 0, stream>>>(x, xb, (M_ROWS * D_MODEL) / 4);
    // 2. transpose-cast weights to [N][K] bf16
    tcast_kernel<<<dim3(192, 64), dim3(32, 8), 0, stream>>>(W_qkv, wqkvT, D_MODEL, 3 * D_MODEL);
    tcast_kernel<<<dim3(64, 64), dim3(32, 8), 0, stream>>>(W_gate, wgateT, D_MODEL, D_MODEL);
    tcast_kernel<<<dim3(64, 64), dim3(32, 8), 0, stream>>>(W_out, woutT, D_MODEL, D_MODEL);
    // 3. QKV GEMM -> q,k [B,H,T,d] ; v transposed [B,H,d,T]
    gemm_bt<0><<<dim3(48, 32), 256, 0, stream>>>(xb, wqkvT, M_ROWS, 3 * D_MODEL, D_MODEL,
                                                 q_b, k_b, v_t, nullptr, nullptr, nullptr, nullptr);
    // 4. RMSNorm + RoPE in place on q,k
    rmsrope_kernel<<<16384, 256, 0, stream>>>(q_b, k_b);
    // 5. causal flash attention -> atty [B,T,D] bf16
    flash_kernel<<<dim3(16, 32), 256, 0, stream>>>(q_b, k_b, v_t, atty);
    // 6. gate GEMM + sigmoid + multiply -> y [B,T,D] bf16
    gemm_bt<1><<<dim3(16, 32), 256, 0, stream>>>(xb, wgateT, M_ROWS, D_MODEL, D_MODEL,
                                                 nullptr, nullptr, nullptr, b_gate, atty, y_b, nullptr);
    // 7. out GEMM -> d_out f32
    gemm_bt<2><<<dim3(16, 32), 256, 0, stream>>>(y_b, woutT, M_ROWS, D_MODEL, D_MODEL,
                                                 nullptr, nullptr, nullptr, nullptr, nullptr, nullptr, out);
}

// Round 2
// 523.703 us; speedup vs baseline: 1.2234x; 1.2234x over previous
//
#include <hip/hip_runtime.h>
#include <stdint.h>

// ---------- types ----------
typedef unsigned short ushort_t;
typedef __bf16 bf16x8 __attribute__((ext_vector_type(8)));
typedef float f32x4 __attribute__((ext_vector_type(4)));
typedef float float4v __attribute__((ext_vector_type(4)));
typedef unsigned short ushort4v __attribute__((ext_vector_type(4)));

#define T_SEQ 2048
#define D_MODEL 2048
#define N_HEADS 16
#define HEAD_D 128
#define BATCH 2
#define M_ROWS (BATCH * T_SEQ)   // 4096

__device__ __forceinline__ ushort_t f2bf(float f) {
    unsigned u = __builtin_bit_cast(unsigned, f);
    u += 0x7fffu + ((u >> 16) & 1u);   // RNE; inputs are finite/sane
    return (ushort_t)(u >> 16);
}
__device__ __forceinline__ float bf2f(ushort_t h) {
    unsigned u = ((unsigned)h) << 16;
    return __builtin_bit_cast(float, u);
}

__device__ __forceinline__ void gload16(const ushort_t* g, ushort_t* l) {
    __builtin_amdgcn_global_load_lds(
        (const __attribute__((address_space(1))) void*)g,
        (__attribute__((address_space(3))) void*)l,
        16, 0, 0);
}

// ---------- cast x: f32 -> bf16 ----------
__global__ void cast_x_kernel(const float* __restrict__ x, ushort_t* __restrict__ xb, int n4) {
    int i = blockIdx.x * blockDim.x + threadIdx.x;
    if (i >= n4) return;
    float4v v = *(const float4v*)(x + (size_t)i * 4);
    ushort4v o;
    o[0] = f2bf(v[0]); o[1] = f2bf(v[1]); o[2] = f2bf(v[2]); o[3] = f2bf(v[3]);
    *(ushort4v*)(xb + (size_t)i * 4) = o;
}

// ---------- transpose + cast: W f32 [K][N] -> Wt bf16 [N][K] ----------
__global__ void tcast_kernel(const float* __restrict__ W, ushort_t* __restrict__ Wt, int K, int N) {
    __shared__ float tile[32][33];
    int n0 = blockIdx.x * 32, k0 = blockIdx.y * 32;
    int tx = threadIdx.x, ty = threadIdx.y;  // block (32,8)
#pragma unroll
    for (int i = 0; i < 4; ++i)
        tile[ty + i * 8][tx] = W[(size_t)(k0 + ty + i * 8) * N + n0 + tx];
    __syncthreads();
#pragma unroll
    for (int i = 0; i < 4; ++i)
        Wt[(size_t)(n0 + ty + i * 8) * K + k0 + tx] = f2bf(tile[tx][ty + i * 8]);
}

// ---------- GEMM: C[M,N] = A[M,K] (bf16 rm) x Bt[N,K] (bf16 rm, = B^T) ----------
template <int EPI>
__global__ __launch_bounds__(256) void gemm_bt(
    const ushort_t* __restrict__ A, const ushort_t* __restrict__ Bt,
    int M, int N, int K,
    ushort_t* __restrict__ o_q, ushort_t* __restrict__ o_k, ushort_t* __restrict__ o_vt,
    const float* __restrict__ b_gate, const ushort_t* __restrict__ atty,
    ushort_t* __restrict__ o_y, float* __restrict__ o_f32)
{
    __shared__ ushort_t As[128 * 64];
    __shared__ ushort_t Bs[128 * 64];
    const int tid = threadIdx.x;
    const int wid = tid >> 6, l = tid & 63;
    const int ln = l & 15, hi = l >> 4;
    const int wm = wid >> 1, wn = wid & 1;
    const int m0 = blockIdx.y * 128, n0 = blockIdx.x * 128;

    f32x4 acc[4][4];
#pragma unroll
    for (int m = 0; m < 4; ++m)
#pragma unroll
        for (int n = 0; n < 4; ++n) acc[m][n] = (f32x4){0.f, 0.f, 0.f, 0.f};

    const ushort_t* Ab = A + (size_t)(m0 + (tid >> 3)) * K + (tid & 7) * 8;
    const ushort_t* Bb = Bt + (size_t)(n0 + (tid >> 3)) * K + (tid & 7) * 8;
    ushort_t* As_w = As + wid * 512;
    ushort_t* Bs_w = Bs + wid * 512;

    for (int kt = 0; kt < K; kt += 64) {
        __syncthreads();
#pragma unroll
        for (int i = 0; i < 4; ++i) {
            gload16(Ab + (size_t)(i * 32) * K + kt, As_w + i * 2048);
            gload16(Bb + (size_t)(i * 32) * K + kt, Bs_w + i * 2048);
        }
        asm volatile("s_waitcnt vmcnt(0)" ::: "memory");
        __syncthreads();
#pragma unroll
        for (int kk = 0; kk < 2; ++kk) {
            bf16x8 af[4], bfg[4];
#pragma unroll
            for (int m = 0; m < 4; ++m)
                af[m] = *(const bf16x8*)(As + (wm * 64 + m * 16 + ln) * 64 + kk * 32 + hi * 8);
#pragma unroll
            for (int n = 0; n < 4; ++n)
                bfg[n] = *(const bf16x8*)(Bs + (wn * 64 + n * 16 + ln) * 64 + kk * 32 + hi * 8);
#pragma unroll
            for (int m = 0; m < 4; ++m)
#pragma unroll
                for (int n = 0; n < 4; ++n)
                    acc[m][n] = __builtin_amdgcn_mfma_f32_16x16x32_bf16(af[m], bfg[n], acc[m][n], 0, 0, 0);
        }
    }

    if (EPI == 0) {
        const int sec = n0 >> 11;
        const int h = (n0 & 2047) >> 7;
#pragma unroll
        for (int m = 0; m < 4; ++m)
#pragma unroll
            for (int n = 0; n < 4; ++n)
#pragma unroll
                for (int j = 0; j < 4; ++j) {
                    int grow = m0 + wm * 64 + m * 16 + hi * 4 + j;
                    int b = grow >> 11, t = grow & 2047;
                    int dd = wn * 64 + n * 16 + ln;
                    ushort_t val = f2bf(acc[m][n][j]);
                    size_t bh = (size_t)(b * N_HEADS + h);
                    if (sec == 0)      o_q[(bh * T_SEQ + t) * HEAD_D + dd] = val;
                    else if (sec == 1) o_k[(bh * T_SEQ + t) * HEAD_D + dd] = val;
                    else               o_vt[(bh * HEAD_D + dd) * T_SEQ + t] = val;
                }
    } else if (EPI == 1) {
#pragma unroll
        for (int m = 0; m < 4; ++m)
#pragma unroll
            for (int n = 0; n < 4; ++n)
#pragma unroll
                for (int j = 0; j < 4; ++j) {
                    int grow = m0 + wm * 64 + m * 16 + hi * 4 + j;
                    int gcol = n0 + wn * 64 + n * 16 + ln;
                    float g = acc[m][n][j] + b_gate[gcol];
                    g = 1.0f / (1.0f + __expf(-g));
                    size_t idx = (size_t)grow * D_MODEL + gcol;
                    o_y[idx] = f2bf(bf2f(atty[idx]) * g);
                }
    } else {
#pragma unroll
        for (int m = 0; m < 4; ++m)
#pragma unroll
            for (int n = 0; n < 4; ++n)
#pragma unroll
                for (int j = 0; j < 4; ++j) {
                    int grow = m0 + wm * 64 + m * 16 + hi * 4 + j;
                    int gcol = n0 + wn * 64 + n * 16 + ln;
                    o_f32[(size_t)grow * N + gcol] = acc[m][n][j];
                }
    }
}

// ---------- RMSNorm + RoPE, in place on q and k [B,H,T,128] ----------
__global__ __launch_bounds__(256) void rmsrope_kernel(ushort_t* __restrict__ qb, ushort_t* __restrict__ kb) {
    int wid = threadIdx.x >> 6, l = threadIdx.x & 63;
    int row = blockIdx.x * 4 + wid;          // (b*H + h)*T + t
    int t = row & (T_SEQ - 1);
    size_t base = (size_t)row * HEAD_D;

    float ang = (float)t * expf(-(float)l * 0.14391156f);
    float sv, cv;
    sincosf(ang, &sv, &cv);

    float a = bf2f(qb[base + l]), b = bf2f(qb[base + 64 + l]);
    float ss = a * a + b * b;
#pragma unroll
    for (int d = 1; d < 64; d <<= 1) ss += __shfl_xor(ss, d);
    float r = rsqrtf(ss * (1.0f / 128.0f) + 1e-6f);
    a *= r; b *= r;
    qb[base + l]      = f2bf(a * cv - b * sv);
    qb[base + 64 + l] = f2bf(a * sv + b * cv);

    a = bf2f(kb[base + l]); b = bf2f(kb[base + 64 + l]);
    ss = a * a + b * b;
#pragma unroll
    for (int d = 1; d < 64; d <<= 1) ss += __shfl_xor(ss, d);
    r = rsqrtf(ss * (1.0f / 128.0f) + 1e-6f);
    a *= r; b *= r;
    kb[base + l]      = f2bf(a * cv - b * sv);
    kb[base + 64 + l] = f2bf(a * sv + b * cv);
}

// ---------- causal flash attention v2 ----------
// grid (16, 32 bh), 256 thr = 4 waves. Balanced quadruples: wave w of block bx
// owns qtile {2bx, 63-2bx, 2bx+1, 62-2bx}[w] (32 q-rows each) -> every block
// does exactly 66 kv-iterations regardless of block->CU assignment.
// Breadth-first shfl reductions; V kk2=0 half hoisted before softmax; exp2 domain.
__global__ __launch_bounds__(256) void flash_kernel(
    const ushort_t* __restrict__ qb, const ushort_t* __restrict__ kb,
    const ushort_t* __restrict__ vt, ushort_t* __restrict__ atty)
{
    const int bx = blockIdx.x, bh = blockIdx.y;
    const int wid = threadIdx.x >> 6, l = threadIdx.x & 63;
    const int ln = l & 15, hi = l >> 4;

    int qtile;
    switch (wid) {
        case 0:  qtile = 2 * bx;      break;
        case 1:  qtile = 63 - 2 * bx; break;
        case 2:  qtile = 2 * bx + 1;  break;
        default: qtile = 62 - 2 * bx; break;
    }
    const int q0 = qtile * 32;
    const int n_tiles = (q0 + 31) / 64 + 1;

    const ushort_t* Q  = qb + (size_t)bh * T_SEQ * HEAD_D;
    const ushort_t* Kp = kb + (size_t)bh * T_SEQ * HEAD_D;
    const ushort_t* Vp = vt + (size_t)bh * HEAD_D * T_SEQ;

    __shared__ ushort_t p_all[4][32][72];
    ushort_t (*p_lds)[72] = p_all[wid];

    bf16x8 qf[2][4];
#pragma unroll
    for (int m = 0; m < 2; ++m)
#pragma unroll
        for (int kk = 0; kk < 4; ++kk)
            qf[m][kk] = *(const bf16x8*)(Q + (size_t)(q0 + m * 16 + ln) * HEAD_D + kk * 32 + hi * 8);

    f32x4 acc_o[2][8];
#pragma unroll
    for (int m = 0; m < 2; ++m)
#pragma unroll
        for (int nd = 0; nd < 8; ++nd) acc_o[m][nd] = (f32x4){0.f, 0.f, 0.f, 0.f};
    float rm[2][4], rl[2][4];
#pragma unroll
    for (int m = 0; m < 2; ++m)
#pragma unroll
        for (int j = 0; j < 4; ++j) { rm[m][j] = -1e30f; rl[m][j] = 0.f; }

    const float scale_log2 = 0.12752059520313818f;   // 1/sqrt(128) * log2(e)

    for (int it = 0; it < n_tiles; ++it) {
        const int kv0 = it * 64;
        // ---- S = Q K^T ----
        f32x4 sa[2][4];
#pragma unroll
        for (int m = 0; m < 2; ++m)
#pragma unroll
            for (int n = 0; n < 4; ++n) sa[m][n] = (f32x4){0.f, 0.f, 0.f, 0.f};
#pragma unroll
        for (int kk = 0; kk < 4; ++kk) {
            bf16x8 kf[4];
#pragma unroll
            for (int n = 0; n < 4; ++n)
                kf[n] = *(const bf16x8*)(Kp + (size_t)(kv0 + n * 16 + ln) * HEAD_D + kk * 32 + hi * 8);
#pragma unroll
            for (int m = 0; m < 2; ++m)
#pragma unroll
                for (int n = 0; n < 4; ++n)
                    sa[m][n] = __builtin_amdgcn_mfma_f32_16x16x32_bf16(qf[m][kk], kf[n], sa[m][n], 0, 0, 0);
        }

        // ---- hoist V (kk2 = 0 half): latency hides under softmax ----
        bf16x8 vf0[8];
#pragma unroll
        for (int nd = 0; nd < 8; ++nd)
            vf0[nd] = *(const bf16x8*)(Vp + (size_t)(nd * 16 + ln) * T_SEQ + kv0 + hi * 8);

        // ---- online softmax, breadth-first reductions (log2 domain) ----
        float pv[2][4][4];   // [m][j][n]
        float mx[2][4];
#pragma unroll
        for (int m = 0; m < 2; ++m)
#pragma unroll
            for (int j = 0; j < 4; ++j) {
                const int qrow = q0 + m * 16 + hi * 4 + j;
                float lmx = -1e30f;
#pragma unroll
                for (int n = 0; n < 4; ++n) {
                    int kv = kv0 + n * 16 + ln;
                    float v = sa[m][n][j] * scale_log2;
                    v = (kv <= qrow) ? v : -1e30f;
                    pv[m][j][n] = v;
                    lmx = fmaxf(lmx, v);
                }
                mx[m][j] = lmx;
            }
#pragma unroll
        for (int d = 1; d < 16; d <<= 1)
#pragma unroll
            for (int m = 0; m < 2; ++m)
#pragma unroll
                for (int j = 0; j < 4; ++j)
                    mx[m][j] = fmaxf(mx[m][j], __shfl_xor(mx[m][j], d));

        float corr[2][4], ps[2][4];
#pragma unroll
        for (int m = 0; m < 2; ++m)
#pragma unroll
            for (int j = 0; j < 4; ++j) {
                float mnew = fmaxf(rm[m][j], mx[m][j]);
                corr[m][j] = __builtin_amdgcn_exp2f(rm[m][j] - mnew);
                rm[m][j] = mnew;
                float psum = 0.f;
#pragma unroll
                for (int n = 0; n < 4; ++n) {
                    float p = __builtin_amdgcn_exp2f(pv[m][j][n] - mnew);
                    psum += p;
                    p_lds[m * 16 + hi * 4 + j][n * 16 + ln] = f2bf(p);
                }
                ps[m][j] = psum;
            }
#pragma unroll
        for (int d = 1; d < 16; d <<= 1)
#pragma unroll
            for (int m = 0; m < 2; ++m)
#pragma unroll
                for (int j = 0; j < 4; ++j)
                    ps[m][j] += __shfl_xor(ps[m][j], d);
#pragma unroll
        for (int m = 0; m < 2; ++m)
#pragma unroll
            for (int j = 0; j < 4; ++j) {
                rl[m][j] = rl[m][j] * corr[m][j] + ps[m][j];
#pragma unroll
                for (int nd = 0; nd < 8; ++nd) acc_o[m][nd][j] *= corr[m][j];
            }

        asm volatile("s_waitcnt lgkmcnt(0)" ::: "memory");  // P writes visible (same wave)

        // ---- O += P V ----
        bf16x8 pA0 = *(const bf16x8*)(&p_lds[ln][hi * 8]);
        bf16x8 pA1 = *(const bf16x8*)(&p_lds[16 + ln][hi * 8]);
        bf16x8 pB0 = *(const bf16x8*)(&p_lds[ln][32 + hi * 8]);
        bf16x8 pB1 = *(const bf16x8*)(&p_lds[16 + ln][32 + hi * 8]);
#pragma unroll
        for (int nd = 0; nd < 8; ++nd) {
            acc_o[0][nd] = __builtin_amdgcn_mfma_f32_16x16x32_bf16(pA0, vf0[nd], acc_o[0][nd], 0, 0, 0);
            acc_o[1][nd] = __builtin_amdgcn_mfma_f32_16x16x32_bf16(pA1, vf0[nd], acc_o[1][nd], 0, 0, 0);
        }
#pragma unroll
        for (int nd = 0; nd < 8; ++nd) {
            bf16x8 vf1 = *(const bf16x8*)(Vp + (size_t)(nd * 16 + ln) * T_SEQ + kv0 + 32 + hi * 8);
            acc_o[0][nd] = __builtin_amdgcn_mfma_f32_16x16x32_bf16(pB0, vf1, acc_o[0][nd], 0, 0, 0);
            acc_o[1][nd] = __builtin_amdgcn_mfma_f32_16x16x32_bf16(pB1, vf1, acc_o[1][nd], 0, 0, 0);
        }
    }

    // epilogue
    const int b = bh >> 4, h = bh & 15;
#pragma unroll
    for (int m = 0; m < 2; ++m)
#pragma unroll
        for (int j = 0; j < 4; ++j) {
            float inv = 1.0f / rl[m][j];
            int tq = q0 + m * 16 + hi * 4 + j;
#pragma unroll
            for (int nd = 0; nd < 8; ++nd)
                atty[((size_t)(b * T_SEQ + tq)) * D_MODEL + h * HEAD_D + nd * 16 + ln] =
                    f2bf(acc_o[m][nd][j] * inv);
        }
}

// ---------- launch ----------
extern "C" void kernel_launch(void* const* d_in, const int* in_sizes, int n_in,
                              void* d_out, int out_size, void* d_ws, size_t ws_size,
                              hipStream_t stream) {
    const float* x      = (const float*)d_in[0];
    const float* W_qkv  = (const float*)d_in[1];
    const float* W_out  = (const float*)d_in[2];
    const float* W_gate = (const float*)d_in[3];
    const float* b_gate = (const float*)d_in[4];
    float* out = (float*)d_out;

    char* ws = (char*)d_ws;
    size_t off = 0;
    ushort_t* xb     = (ushort_t*)(ws + off); off += (size_t)M_ROWS * D_MODEL * 2;
    ushort_t* wqkvT  = (ushort_t*)(ws + off); off += (size_t)3 * D_MODEL * D_MODEL * 2;
    ushort_t* wgateT = (ushort_t*)(ws + off); off += (size_t)D_MODEL * D_MODEL * 2;
    ushort_t* woutT  = (ushort_t*)(ws + off); off += (size_t)D_MODEL * D_MODEL * 2;
    ushort_t* q_b    = (ushort_t*)(ws + off); off += (size_t)M_ROWS * D_MODEL * 2;
    ushort_t* k_b    = (ushort_t*)(ws + off); off += (size_t)M_ROWS * D_MODEL * 2;
    ushort_t* v_t    = (ushort_t*)(ws + off); off += (size_t)M_ROWS * D_MODEL * 2;
    ushort_t* atty   = (ushort_t*)(ws + off); off += (size_t)M_ROWS * D_MODEL * 2;
    ushort_t* y_b    = (ushort_t*)(ws + off); off += (size_t)M_ROWS * D_MODEL * 2;

    cast_x_kernel<<<8192, 256, 0, stream>>>(x, xb, (M_ROWS * D_MODEL) / 4);
    tcast_kernel<<<dim3(192, 64), dim3(32, 8), 0, stream>>>(W_qkv, wqkvT, D_MODEL, 3 * D_MODEL);
    tcast_kernel<<<dim3(64, 64), dim3(32, 8), 0, stream>>>(W_gate, wgateT, D_MODEL, D_MODEL);
    tcast_kernel<<<dim3(64, 64), dim3(32, 8), 0, stream>>>(W_out, woutT, D_MODEL, D_MODEL);
    gemm_bt<0><<<dim3(48, 32), 256, 0, stream>>>(xb, wqkvT, M_ROWS, 3 * D_MODEL, D_MODEL,
                                                 q_b, k_b, v_t, nullptr, nullptr, nullptr, nullptr);
    rmsrope_kernel<<<16384, 256, 0, stream>>>(q_b, k_b);
    flash_kernel<<<dim3(16, 32), 256, 0, stream>>>(q_b, k_b, v_t, atty);
    gemm_bt<1><<<dim3(16, 32), 256, 0, stream>>>(xb, wgateT, M_ROWS, D_MODEL, D_MODEL,
                                                 nullptr, nullptr, nullptr, b_gate, atty, y_b, nullptr);
    gemm_bt<2><<<dim3(16, 32), 256, 0, stream>>>(y_b, woutT, M_ROWS, D_MODEL, D_MODEL,
                                                 nullptr, nullptr, nullptr, nullptr, nullptr, nullptr, out);
}